// Round 2
// baseline (365.841 us; speedup 1.0000x reference)
//
#include <hip/hip_runtime.h>
#include <hip/hip_bf16.h>
#include <math.h>

#define NT 32
#define NSTEP 31
#define DD 384
#define HH 128
#define KK 128
#define MBATCH 8
#define NPIX 65536   // 256*256
#define W2LD 132     // padded LDS row stride for W2 (2-way bank alias only)

// ---------------- DPP row reductions (VALU-only, no LDS pipe) ----------------
template<int CTRL>
__device__ __forceinline__ float dpp_add(float v) {
  int m = __builtin_amdgcn_update_dpp(0, __float_as_int(v), CTRL, 0xf, 0xf, true);
  return v + __int_as_float(m);
}
__device__ __forceinline__ float red16(float v) {
  v = dpp_add<0xB1>(v);   // xor 1
  v = dpp_add<0x4E>(v);   // xor 2
  v = dpp_add<0x141>(v);  // xor 4 (within 8)
  v = dpp_add<0x140>(v);  // xor 8 (within 16)
  return v;
}
__device__ __forceinline__ float red8(float v) {
  v = dpp_add<0xB1>(v);
  v = dpp_add<0x4E>(v);
  v = dpp_add<0x141>(v);
  return v;
}

// ---------------- Kernel 1: serial RK4 (3/8 rule) ODE, 1 block --------------
// W1,W3 resident in VGPRs (96+96/lane, fits 256-VGPR cap); W2 in LDS.
// RK combiner folded into L1 (x built on the fly from sh_y/sh_k).
__global__ __launch_bounds__(512, 2) void ode_kernel(
    const float* __restrict__ tarr, const float* __restrict__ ic,
    const float* __restrict__ W1, const float* __restrict__ b1,
    const float* __restrict__ W2, const float* __restrict__ b2,
    const float* __restrict__ W3, const float* __restrict__ b3,
    float* __restrict__ coeffT)   // [3][128][32] = [c][k][t]
{
  __shared__ __align__(16) float sh_h1[HH];
  __shared__ __align__(16) float sh_h2[HH];
  __shared__ __align__(16) float sh_k[4][DD];
  __shared__ __align__(16) float sh_y[DD];
  __shared__ __align__(16) float sh_b1[HH];
  __shared__ __align__(16) float sh_b2[HH];
  __shared__ __align__(16) float sh_b3[DD];
  __shared__ float sh_t[NT];
  __shared__ __align__(16) float sh_w2[HH * W2LD];  // ~67.6 KB

  const int tid = threadIdx.x;
  const int w   = tid >> 6;   // wave 0..7
  const int l   = tid & 63;   // lane

  if (tid < HH) { sh_b1[tid] = b1[tid]; sh_b2[tid] = b2[tid]; }
  if (tid < DD) {
    sh_b3[tid] = b3[tid];
    float y0 = ic[tid];
    sh_y[tid] = y0;
    coeffT[(tid % 3) * (KK * NT) + (tid / 3) * NT + 0] = y0;  // t = 0
  }
  if (tid < NT) sh_t[tid] = tarr[tid];

  // ---- stage W2 into LDS (padded rows) ----
  {
    const int r  = tid >> 2;         // 0..127
    const int i0 = (tid & 3) * 32;   // 0,32,64,96
    #pragma unroll
    for (int q = 0; q < 8; ++q) {
      float4 v = *(const float4*)&W2[r * HH + i0 + q * 4];
      *(float4*)&sh_w2[r * W2LD + i0 + q * 4] = v;
    }
  }

  // ---- per-lane weight residency (W1, W3 only) ----
  const int jg  = l >> 4, il  = l & 15;
  const int jg3 = l >> 3, il3 = l & 7;
  const int j1 = w * 16 + jg * 4;
  const int j3 = w * 48 + jg3 * 6;

  float w1r[96], w3r[96];
  #pragma unroll
  for (int o = 0; o < 4; ++o)
    #pragma unroll
    for (int ii = 0; ii < 24; ++ii)
      w1r[o * 24 + ii] = W1[(j1 + o) * DD + il * 24 + ii];
  #pragma unroll
  for (int o = 0; o < 6; ++o)
    #pragma unroll
    for (int ii = 0; ii < 16; ++ii)
      w3r[o * 16 + ii] = W3[(j3 + o) * HH + il3 * 16 + ii];

  __syncthreads();

  for (int step = 0; step < NSTEP; ++step) {
    const float dt  = sh_t[step + 1] - sh_t[step];
    const float dt3 = dt * (1.0f / 3.0f);
    #pragma unroll
    for (int s = 0; s < 4; ++s) {
      // ---- L1 (combiner folded): h1 = relu(W1 x + b1) ----
      {
        float acc[4] = {0.f, 0.f, 0.f, 0.f};
        #pragma unroll
        for (int q = 0; q < 6; ++q) {
          const int base = il * 24 + q * 4;
          float4 yv = *(const float4*)&sh_y[base];
          float xs[4];
          if (s == 0) {
            xs[0] = yv.x; xs[1] = yv.y; xs[2] = yv.z; xs[3] = yv.w;
          } else if (s == 1) {
            float4 k0 = *(const float4*)&sh_k[0][base];
            xs[0] = fmaf(dt3, k0.x, yv.x);
            xs[1] = fmaf(dt3, k0.y, yv.y);
            xs[2] = fmaf(dt3, k0.z, yv.z);
            xs[3] = fmaf(dt3, k0.w, yv.w);
          } else if (s == 2) {
            float4 k0 = *(const float4*)&sh_k[0][base];
            float4 k1 = *(const float4*)&sh_k[1][base];
            xs[0] = fmaf(dt, k1.x - (1.0f/3.0f) * k0.x, yv.x);
            xs[1] = fmaf(dt, k1.y - (1.0f/3.0f) * k0.y, yv.y);
            xs[2] = fmaf(dt, k1.z - (1.0f/3.0f) * k0.z, yv.z);
            xs[3] = fmaf(dt, k1.w - (1.0f/3.0f) * k0.w, yv.w);
          } else {
            float4 k0 = *(const float4*)&sh_k[0][base];
            float4 k1 = *(const float4*)&sh_k[1][base];
            float4 k2 = *(const float4*)&sh_k[2][base];
            xs[0] = fmaf(dt, k0.x - k1.x + k2.x, yv.x);
            xs[1] = fmaf(dt, k0.y - k1.y + k2.y, yv.y);
            xs[2] = fmaf(dt, k0.z - k1.z + k2.z, yv.z);
            xs[3] = fmaf(dt, k0.w - k1.w + k2.w, yv.w);
          }
          #pragma unroll
          for (int e = 0; e < 4; ++e)
            #pragma unroll
            for (int o = 0; o < 4; ++o)
              acc[o] = fmaf(w1r[o * 24 + q * 4 + e], xs[e], acc[o]);
        }
        acc[0] = red16(acc[0]); acc[1] = red16(acc[1]);
        acc[2] = red16(acc[2]); acc[3] = red16(acc[3]);
        if (il == 0) {
          float4 hv;
          hv.x = fmaxf(acc[0] + sh_b1[j1 + 0], 0.f);
          hv.y = fmaxf(acc[1] + sh_b1[j1 + 1], 0.f);
          hv.z = fmaxf(acc[2] + sh_b1[j1 + 2], 0.f);
          hv.w = fmaxf(acc[3] + sh_b1[j1 + 3], 0.f);
          *(float4*)&sh_h1[j1] = hv;
        }
      }
      __syncthreads();

      // ---- L2: h2 = elu(W2 h1 + b2), W2 streamed from LDS ----
      {
        float acc[4] = {0.f, 0.f, 0.f, 0.f};
        #pragma unroll
        for (int q = 0; q < 2; ++q) {
          float4 xv = *(const float4*)&sh_h1[il * 8 + q * 4];
          float xs[4] = {xv.x, xv.y, xv.z, xv.w};
          #pragma unroll
          for (int o = 0; o < 4; ++o) {
            float4 wv = *(const float4*)&sh_w2[(j1 + o) * W2LD + il * 8 + q * 4];
            acc[o] = fmaf(wv.x, xs[0], acc[o]);
            acc[o] = fmaf(wv.y, xs[1], acc[o]);
            acc[o] = fmaf(wv.z, xs[2], acc[o]);
            acc[o] = fmaf(wv.w, xs[3], acc[o]);
          }
        }
        acc[0] = red16(acc[0]); acc[1] = red16(acc[1]);
        acc[2] = red16(acc[2]); acc[3] = red16(acc[3]);
        if (il == 0) {
          float4 hv;
          float v0 = acc[0] + sh_b2[j1 + 0]; hv.x = v0 > 0.f ? v0 : expm1f(v0);
          float v1 = acc[1] + sh_b2[j1 + 1]; hv.y = v1 > 0.f ? v1 : expm1f(v1);
          float v2 = acc[2] + sh_b2[j1 + 2]; hv.z = v2 > 0.f ? v2 : expm1f(v2);
          float v3 = acc[3] + sh_b2[j1 + 3]; hv.w = v3 > 0.f ? v3 : expm1f(v3);
          *(float4*)&sh_h2[j1] = hv;
        }
      }
      __syncthreads();

      // ---- L3: k_s = W3 h2 + b3 ----
      {
        float acc[6] = {0.f, 0.f, 0.f, 0.f, 0.f, 0.f};
        #pragma unroll
        for (int q = 0; q < 4; ++q) {
          float4 xv = *(const float4*)&sh_h2[il3 * 16 + q * 4];
          float xs[4] = {xv.x, xv.y, xv.z, xv.w};
          #pragma unroll
          for (int e = 0; e < 4; ++e)
            #pragma unroll
            for (int o = 0; o < 6; ++o)
              acc[o] = fmaf(w3r[o * 16 + q * 4 + e], xs[e], acc[o]);
        }
        #pragma unroll
        for (int o = 0; o < 6; ++o) acc[o] = red8(acc[o]);
        if (il3 == 0) {
          #pragma unroll
          for (int o = 0; o < 6; ++o)
            sh_k[s][j3 + o] = acc[o] + sh_b3[j3 + o];
        }
      }
      __syncthreads();
    } // stages

    // ---- y update + emit coeff for step+1 ----
    if (tid < DD) {
      float y = sh_y[tid];
      y = y + dt * 0.125f *
              (sh_k[0][tid] + 3.f * (sh_k[1][tid] + sh_k[2][tid]) + sh_k[3][tid]);
      sh_y[tid] = y;
      coeffT[(tid % 3) * (KK * NT) + (tid / 3) * NT + (step + 1)] = y;
    }
    __syncthreads();
  }
}

// ---------------- Kernel 2: out[t,m,c,p] = sum_k coeffT[c][k][t]*basis[k,c,p]
__global__ __launch_bounds__(256, 4) void einsum_kernel(
    const float* __restrict__ basis, const float* __restrict__ coeffT,
    float* __restrict__ out)
{
  __shared__ __align__(16) float sh_c[KK * NT];  // [k][t] for this c, 16KB
  const int tid = threadIdx.x;
  const int bid = blockIdx.x;
  const int c = bid >> 8;        // 0..2
  const int ptile = bid & 255;   // 0..255, 256 pixels each

  const float* cT = coeffT + c * (KK * NT);
  #pragma unroll
  for (int q = 0; q < 4; ++q)
    *(float4*)&sh_c[tid * 16 + q * 4] = *(const float4*)&cT[tid * 16 + q * 4];
  __syncthreads();

  const int slot = tid & 31;   // 32 slots x 8 px = 256 px
  const int tg   = tid >> 5;   // 8 groups x 4 t  = 32 t
  const int px0  = ptile * 256 + slot * 8;
  const float* bp = basis + (size_t)c * NPIX + px0;

  float acc[4][8];
  #pragma unroll
  for (int t = 0; t < 4; ++t)
    #pragma unroll
    for (int p = 0; p < 8; ++p) acc[t][p] = 0.f;

  #pragma unroll 4
  for (int k = 0; k < KK; ++k) {
    const float* bk = bp + (size_t)k * (3 * NPIX);
    float4 b0 = *(const float4*)(bk);
    float4 b1v = *(const float4*)(bk + 4);
    float4 cv = *(const float4*)&sh_c[k * NT + tg * 4];
    float cs[4] = {cv.x, cv.y, cv.z, cv.w};
    float bs[8] = {b0.x, b0.y, b0.z, b0.w, b1v.x, b1v.y, b1v.z, b1v.w};
    #pragma unroll
    for (int t = 0; t < 4; ++t)
      #pragma unroll
      for (int p = 0; p < 8; ++p)
        acc[t][p] = fmaf(cs[t], bs[p], acc[t][p]);
  }

  #pragma unroll
  for (int t = 0; t < 4; ++t) {
    const int tt = tg * 4 + t;
    #pragma unroll
    for (int m = 0; m < MBATCH; ++m) {
      float* op = out + (((size_t)(tt * MBATCH + m) * 3 + c) << 16) + px0;
      *(float4*)(op)     = make_float4(acc[t][0], acc[t][1], acc[t][2], acc[t][3]);
      *(float4*)(op + 4) = make_float4(acc[t][4], acc[t][5], acc[t][6], acc[t][7]);
    }
  }
}

extern "C" void kernel_launch(void* const* d_in, const int* in_sizes, int n_in,
                              void* d_out, int out_size, void* d_ws, size_t ws_size,
                              hipStream_t stream) {
  (void)in_sizes; (void)n_in; (void)out_size; (void)ws_size;
  // setup_inputs order: grid0, t, init_coeffs, W1, b1, W2, b2, W3, b3, basis
  const float* tarr  = (const float*)d_in[1];
  const float* ic    = (const float*)d_in[2];
  const float* W1    = (const float*)d_in[3];
  const float* b1    = (const float*)d_in[4];
  const float* W2    = (const float*)d_in[5];
  const float* b2    = (const float*)d_in[6];
  const float* W3    = (const float*)d_in[7];
  const float* b3    = (const float*)d_in[8];
  const float* basis = (const float*)d_in[9];
  float* coeffT = (float*)d_ws;          // 3*128*32 floats = 48 KB
  float* out    = (float*)d_out;

  hipLaunchKernelGGL(ode_kernel, dim3(1), dim3(512), 0, stream,
                     tarr, ic, W1, b1, W2, b2, W3, b3, coeffT);
  hipLaunchKernelGGL(einsum_kernel, dim3(768), dim3(256), 0, stream,
                     basis, coeffT, out);
}

// Round 3
// 364.718 us; speedup vs baseline: 1.0031x; 1.0031x over previous
//
#include <hip/hip_runtime.h>
#include <hip/hip_bf16.h>
#include <math.h>

#define NT 32
#define NSTEP 31
#define DD 384
#define HH 128
#define KK 128
#define MBATCH 8
#define NPIX 65536   // 256*256
#define W2LD 132     // padded LDS row stride for W2 (2-way bank alias only)

// ---------------- DPP row reductions (VALU-only, no LDS pipe) ----------------
template<int CTRL>
__device__ __forceinline__ float dpp_add(float v) {
  int m = __builtin_amdgcn_update_dpp(0, __float_as_int(v), CTRL, 0xf, 0xf, true);
  return v + __int_as_float(m);
}
__device__ __forceinline__ float red16(float v) {
  v = dpp_add<0xB1>(v);   // xor 1
  v = dpp_add<0x4E>(v);   // xor 2
  v = dpp_add<0x141>(v);  // xor 4 (within 8)
  v = dpp_add<0x140>(v);  // xor 8 (within 16)
  return v;
}
__device__ __forceinline__ float red8(float v) {
  v = dpp_add<0xB1>(v);
  v = dpp_add<0x4E>(v);
  v = dpp_add<0x141>(v);
  return v;
}

// ---------------- Kernel 1: serial RK4 (3/8 rule) ODE, 1 block --------------
// W1,W3 resident in VGPRs (96+96/lane); W2 in LDS. __launch_bounds__(512,1)
// -> 2 waves/SIMD -> 256-VGPR cap so the weight arrays actually stay resident.
__global__ __launch_bounds__(512, 1) void ode_kernel(
    const float* __restrict__ tarr, const float* __restrict__ ic,
    const float* __restrict__ W1, const float* __restrict__ b1,
    const float* __restrict__ W2, const float* __restrict__ b2,
    const float* __restrict__ W3, const float* __restrict__ b3,
    float* __restrict__ coeffT)   // [3][128][32] = [c][k][t]
{
  __shared__ __align__(16) float sh_h1[HH];
  __shared__ __align__(16) float sh_h2[HH];
  __shared__ __align__(16) float sh_k[4][DD];
  __shared__ __align__(16) float sh_y[DD];
  __shared__ __align__(16) float sh_b1[HH];
  __shared__ __align__(16) float sh_b2[HH];
  __shared__ __align__(16) float sh_b3[DD];
  __shared__ float sh_t[NT];
  __shared__ __align__(16) float sh_w2[HH * W2LD];  // ~67.6 KB

  const int tid = threadIdx.x;
  const int w   = tid >> 6;   // wave 0..7
  const int l   = tid & 63;   // lane

  if (tid < HH) { sh_b1[tid] = b1[tid]; sh_b2[tid] = b2[tid]; }
  if (tid < DD) {
    sh_b3[tid] = b3[tid];
    float y0 = ic[tid];
    sh_y[tid] = y0;
    coeffT[(tid % 3) * (KK * NT) + (tid / 3) * NT + 0] = y0;  // t = 0
  }
  if (tid < NT) sh_t[tid] = tarr[tid];

  // ---- stage W2 into LDS (padded rows) ----
  {
    const int r  = tid >> 2;         // 0..127
    const int i0 = (tid & 3) * 32;   // 0,32,64,96
    #pragma unroll
    for (int q = 0; q < 8; ++q) {
      float4 v = *(const float4*)&W2[r * HH + i0 + q * 4];
      *(float4*)&sh_w2[r * W2LD + i0 + q * 4] = v;
    }
  }

  // ---- per-lane weight residency (W1, W3 only) ----
  const int jg  = l >> 4, il  = l & 15;
  const int jg3 = l >> 3, il3 = l & 7;
  const int j1 = w * 16 + jg * 4;
  const int j3 = w * 48 + jg3 * 6;

  float w1r[96], w3r[96];
  #pragma unroll
  for (int o = 0; o < 4; ++o)
    #pragma unroll
    for (int ii = 0; ii < 24; ++ii)
      w1r[o * 24 + ii] = W1[(j1 + o) * DD + il * 24 + ii];
  #pragma unroll
  for (int o = 0; o < 6; ++o)
    #pragma unroll
    for (int ii = 0; ii < 16; ++ii)
      w3r[o * 16 + ii] = W3[(j3 + o) * HH + il3 * 16 + ii];

  __syncthreads();

  for (int step = 0; step < NSTEP; ++step) {
    const float dt  = sh_t[step + 1] - sh_t[step];
    const float dt3 = dt * (1.0f / 3.0f);
    #pragma unroll
    for (int s = 0; s < 4; ++s) {
      // ---- L1 (combiner folded): h1 = relu(W1 x + b1) ----
      {
        float acc[4] = {0.f, 0.f, 0.f, 0.f};
        #pragma unroll
        for (int q = 0; q < 6; ++q) {
          const int base = il * 24 + q * 4;
          float4 yv = *(const float4*)&sh_y[base];
          float xs[4];
          if (s == 0) {
            xs[0] = yv.x; xs[1] = yv.y; xs[2] = yv.z; xs[3] = yv.w;
          } else if (s == 1) {
            float4 k0 = *(const float4*)&sh_k[0][base];
            xs[0] = fmaf(dt3, k0.x, yv.x);
            xs[1] = fmaf(dt3, k0.y, yv.y);
            xs[2] = fmaf(dt3, k0.z, yv.z);
            xs[3] = fmaf(dt3, k0.w, yv.w);
          } else if (s == 2) {
            float4 k0 = *(const float4*)&sh_k[0][base];
            float4 k1 = *(const float4*)&sh_k[1][base];
            xs[0] = fmaf(dt, k1.x - (1.0f/3.0f) * k0.x, yv.x);
            xs[1] = fmaf(dt, k1.y - (1.0f/3.0f) * k0.y, yv.y);
            xs[2] = fmaf(dt, k1.z - (1.0f/3.0f) * k0.z, yv.z);
            xs[3] = fmaf(dt, k1.w - (1.0f/3.0f) * k0.w, yv.w);
          } else {
            float4 k0 = *(const float4*)&sh_k[0][base];
            float4 k1 = *(const float4*)&sh_k[1][base];
            float4 k2 = *(const float4*)&sh_k[2][base];
            xs[0] = fmaf(dt, k0.x - k1.x + k2.x, yv.x);
            xs[1] = fmaf(dt, k0.y - k1.y + k2.y, yv.y);
            xs[2] = fmaf(dt, k0.z - k1.z + k2.z, yv.z);
            xs[3] = fmaf(dt, k0.w - k1.w + k2.w, yv.w);
          }
          #pragma unroll
          for (int e = 0; e < 4; ++e)
            #pragma unroll
            for (int o = 0; o < 4; ++o)
              acc[o] = fmaf(w1r[o * 24 + q * 4 + e], xs[e], acc[o]);
        }
        acc[0] = red16(acc[0]); acc[1] = red16(acc[1]);
        acc[2] = red16(acc[2]); acc[3] = red16(acc[3]);
        if (il == 0) {
          float4 hv;
          hv.x = fmaxf(acc[0] + sh_b1[j1 + 0], 0.f);
          hv.y = fmaxf(acc[1] + sh_b1[j1 + 1], 0.f);
          hv.z = fmaxf(acc[2] + sh_b1[j1 + 2], 0.f);
          hv.w = fmaxf(acc[3] + sh_b1[j1 + 3], 0.f);
          *(float4*)&sh_h1[j1] = hv;
        }
      }
      __syncthreads();

      // ---- L2: h2 = elu(W2 h1 + b2), W2 streamed from LDS ----
      {
        float acc[4] = {0.f, 0.f, 0.f, 0.f};
        #pragma unroll
        for (int q = 0; q < 2; ++q) {
          float4 xv = *(const float4*)&sh_h1[il * 8 + q * 4];
          float xs[4] = {xv.x, xv.y, xv.z, xv.w};
          #pragma unroll
          for (int o = 0; o < 4; ++o) {
            float4 wv = *(const float4*)&sh_w2[(j1 + o) * W2LD + il * 8 + q * 4];
            acc[o] = fmaf(wv.x, xs[0], acc[o]);
            acc[o] = fmaf(wv.y, xs[1], acc[o]);
            acc[o] = fmaf(wv.z, xs[2], acc[o]);
            acc[o] = fmaf(wv.w, xs[3], acc[o]);
          }
        }
        acc[0] = red16(acc[0]); acc[1] = red16(acc[1]);
        acc[2] = red16(acc[2]); acc[3] = red16(acc[3]);
        if (il == 0) {
          float4 hv;
          float v0 = acc[0] + sh_b2[j1 + 0]; hv.x = v0 > 0.f ? v0 : expm1f(v0);
          float v1 = acc[1] + sh_b2[j1 + 1]; hv.y = v1 > 0.f ? v1 : expm1f(v1);
          float v2 = acc[2] + sh_b2[j1 + 2]; hv.z = v2 > 0.f ? v2 : expm1f(v2);
          float v3 = acc[3] + sh_b2[j1 + 3]; hv.w = v3 > 0.f ? v3 : expm1f(v3);
          *(float4*)&sh_h2[j1] = hv;
        }
      }
      __syncthreads();

      // ---- L3: k_s = W3 h2 + b3 ----
      {
        float acc[6] = {0.f, 0.f, 0.f, 0.f, 0.f, 0.f};
        #pragma unroll
        for (int q = 0; q < 4; ++q) {
          float4 xv = *(const float4*)&sh_h2[il3 * 16 + q * 4];
          float xs[4] = {xv.x, xv.y, xv.z, xv.w};
          #pragma unroll
          for (int e = 0; e < 4; ++e)
            #pragma unroll
            for (int o = 0; o < 6; ++o)
              acc[o] = fmaf(w3r[o * 16 + q * 4 + e], xs[e], acc[o]);
        }
        #pragma unroll
        for (int o = 0; o < 6; ++o) acc[o] = red8(acc[o]);
        if (il3 == 0) {
          #pragma unroll
          for (int o = 0; o < 6; ++o)
            sh_k[s][j3 + o] = acc[o] + sh_b3[j3 + o];
        }
      }
      __syncthreads();
    } // stages

    // ---- y update + emit coeff for step+1 ----
    if (tid < DD) {
      float y = sh_y[tid];
      y = y + dt * 0.125f *
              (sh_k[0][tid] + 3.f * (sh_k[1][tid] + sh_k[2][tid]) + sh_k[3][tid]);
      sh_y[tid] = y;
      coeffT[(tid % 3) * (KK * NT) + (tid / 3) * NT + (step + 1)] = y;
    }
    __syncthreads();
  }
}

// ---------------- Kernel 2: out[t,m,c,p] = sum_k coeffT[c][k][t]*basis[k,c,p]
__global__ __launch_bounds__(256, 4) void einsum_kernel(
    const float* __restrict__ basis, const float* __restrict__ coeffT,
    float* __restrict__ out)
{
  __shared__ __align__(16) float sh_c[KK * NT];  // [k][t] for this c, 16KB
  const int tid = threadIdx.x;
  const int bid = blockIdx.x;
  const int c = bid >> 8;        // 0..2
  const int ptile = bid & 255;   // 0..255, 256 pixels each

  const float* cT = coeffT + c * (KK * NT);
  #pragma unroll
  for (int q = 0; q < 4; ++q)
    *(float4*)&sh_c[tid * 16 + q * 4] = *(const float4*)&cT[tid * 16 + q * 4];
  __syncthreads();

  const int slot = tid & 31;   // 32 slots x 8 px = 256 px
  const int tg   = tid >> 5;   // 8 groups x 4 t  = 32 t
  const int px0  = ptile * 256 + slot * 8;
  const float* bp = basis + (size_t)c * NPIX + px0;

  float acc[4][8];
  #pragma unroll
  for (int t = 0; t < 4; ++t)
    #pragma unroll
    for (int p = 0; p < 8; ++p) acc[t][p] = 0.f;

  #pragma unroll 4
  for (int k = 0; k < KK; ++k) {
    const float* bk = bp + (size_t)k * (3 * NPIX);
    float4 b0 = *(const float4*)(bk);
    float4 b1v = *(const float4*)(bk + 4);
    float4 cv = *(const float4*)&sh_c[k * NT + tg * 4];
    float cs[4] = {cv.x, cv.y, cv.z, cv.w};
    float bs[8] = {b0.x, b0.y, b0.z, b0.w, b1v.x, b1v.y, b1v.z, b1v.w};
    #pragma unroll
    for (int t = 0; t < 4; ++t)
      #pragma unroll
      for (int p = 0; p < 8; ++p)
        acc[t][p] = fmaf(cs[t], bs[p], acc[t][p]);
  }

  #pragma unroll
  for (int t = 0; t < 4; ++t) {
    const int tt = tg * 4 + t;
    #pragma unroll
    for (int m = 0; m < MBATCH; ++m) {
      float* op = out + (((size_t)(tt * MBATCH + m) * 3 + c) << 16) + px0;
      *(float4*)(op)     = make_float4(acc[t][0], acc[t][1], acc[t][2], acc[t][3]);
      *(float4*)(op + 4) = make_float4(acc[t][4], acc[t][5], acc[t][6], acc[t][7]);
    }
  }
}

extern "C" void kernel_launch(void* const* d_in, const int* in_sizes, int n_in,
                              void* d_out, int out_size, void* d_ws, size_t ws_size,
                              hipStream_t stream) {
  (void)in_sizes; (void)n_in; (void)out_size; (void)ws_size;
  // setup_inputs order: grid0, t, init_coeffs, W1, b1, W2, b2, W3, b3, basis
  const float* tarr  = (const float*)d_in[1];
  const float* ic    = (const float*)d_in[2];
  const float* W1    = (const float*)d_in[3];
  const float* b1    = (const float*)d_in[4];
  const float* W2    = (const float*)d_in[5];
  const float* b2    = (const float*)d_in[6];
  const float* W3    = (const float*)d_in[7];
  const float* b3    = (const float*)d_in[8];
  const float* basis = (const float*)d_in[9];
  float* coeffT = (float*)d_ws;          // 3*128*32 floats = 48 KB
  float* out    = (float*)d_out;

  hipLaunchKernelGGL(ode_kernel, dim3(1), dim3(512), 0, stream,
                     tarr, ic, W1, b1, W2, b2, W3, b3, coeffT);
  hipLaunchKernelGGL(einsum_kernel, dim3(768), dim3(256), 0, stream,
                     basis, coeffT, out);
}

// Round 4
// 284.621 us; speedup vs baseline: 1.2854x; 1.2814x over previous
//
#include <hip/hip_runtime.h>
#include <hip/hip_bf16.h>
#include <math.h>

#define NT 32
#define NSTEP 31
#define DD 384
#define HH 128
#define KK 128
#define MBATCH 8
#define NPIX 65536   // 256*256

typedef float f32x4 __attribute__((ext_vector_type(4)));
typedef short bf16x8 __attribute__((ext_vector_type(8)));

__device__ __forceinline__ unsigned short f2bf(float f) {
  unsigned u = __float_as_uint(f);
  return (unsigned short)((u + 0x7FFFu + ((u >> 16) & 1u)) >> 16);  // RNE
}
__device__ __forceinline__ unsigned pk2(float a, float b) {
  return (unsigned)f2bf(a) | ((unsigned)f2bf(b) << 16);
}
__device__ __forceinline__ bf16x8 pack8(const float* p) {
  bf16x8 v;
  #pragma unroll
  for (int j = 0; j < 8; ++j) v[j] = (short)f2bf(p[j]);
  return v;
}

// ---------------- Kernel 1: serial RK4 (3/8 rule) ODE, 1 block, MFMA MLP ----
// Wave w owns rows 16w..16w+15 of L1/L2 outputs and rows 48w..48w+47 of L3.
// B operand = activation vector replicated across all 16 MFMA columns, so
// every lane's B-fragment is 8 contiguous bf16 (LDS broadcast read) and the
// D fragment holds h[16w+4g+r] replicated across column-lanes.
// W1 fragments live in LDS (96 KB); W2/W3 fragments in VGPRs (64 regs bf16).
__global__ __launch_bounds__(512, 1) void ode_kernel(
    const float* __restrict__ tarr, const float* __restrict__ ic,
    const float* __restrict__ W1, const float* __restrict__ b1,
    const float* __restrict__ W2, const float* __restrict__ b2,
    const float* __restrict__ W3, const float* __restrict__ b3,
    float* __restrict__ coeffT)   // [3][128][32] = [c][k][t]
{
  __shared__ bf16x8 sh_w1[8 * 12 * 64];                  // 96 KB: [w][chunk][lane]
  __shared__ __align__(16) float sh_y[DD];
  __shared__ __align__(16) float sh_k[4][DD];
  __shared__ __align__(16) float sh_b1[HH], sh_b2[HH], sh_b3[DD];
  __shared__ float sh_t[NT];
  __shared__ __align__(16) unsigned short sh_x[DD];      // bf16 MLP input
  __shared__ __align__(16) unsigned sh_h1u[HH / 2];      // bf16 h1 (packed)
  __shared__ __align__(16) unsigned sh_h2u[HH / 2];      // bf16 h2 (packed)

  const int tid = threadIdx.x;
  const int w = tid >> 6, l = tid & 63;
  const int r16 = l & 15, g = l >> 4;

  for (int i = tid; i < HH; i += 512) { sh_b1[i] = b1[i]; sh_b2[i] = b2[i]; }
  for (int i = tid; i < DD; i += 512) {
    sh_b3[i] = b3[i];
    float y0 = ic[i];
    sh_y[i] = y0;
    sh_x[i] = f2bf(y0);
    coeffT[(i % 3) * (KK * NT) + (i / 3) * NT + 0] = y0;  // t = 0
  }
  if (tid < NT) sh_t[tid] = tarr[tid];

  // ---- build W1 fragments into LDS: frag(w',c)[lane] elem j =
  //      bf16(W1[16w' + (lane&15)][32c + 8*(lane>>4) + j])
  for (int idx = tid; idx < 8 * 12 * 64; idx += 512) {
    const int lw = idx & 63, tmp = idx >> 6;
    const int c = tmp % 12, ww = tmp / 12;
    const float* src = W1 + (16 * ww + (lw & 15)) * DD + 32 * c + 8 * (lw >> 4);
    sh_w1[idx] = pack8(src);
  }

  // ---- W2/W3 fragments in registers (bf16-packed, 16 + 48 VGPRs) ----
  bf16x8 w2f[4], w3f[3][4];
  #pragma unroll
  for (int c = 0; c < 4; ++c)
    w2f[c] = pack8(W2 + (16 * w + r16) * HH + 32 * c + 8 * g);
  #pragma unroll
  for (int t = 0; t < 3; ++t)
    #pragma unroll
    for (int c = 0; c < 4; ++c)
      w3f[t][c] = pack8(W3 + (48 * w + 16 * t + r16) * HH + 32 * c + 8 * g);

  __syncthreads();

  for (int step = 0; step < NSTEP; ++step) {
    const float dt  = sh_t[step + 1] - sh_t[step];
    const float dt3 = dt * (1.0f / 3.0f);
    #pragma unroll
    for (int s = 0; s < 4; ++s) {
      // ---- combiner: build bf16 input x for this RK stage (s=0 uses sh_x=y,
      //      already written by init / previous y-update) ----
      if (s > 0) {
        if (tid < DD) {
          float y = sh_y[tid], x;
          if (s == 1)      x = fmaf(dt3, sh_k[0][tid], y);
          else if (s == 2) x = fmaf(dt, sh_k[1][tid] - (1.0f/3.0f) * sh_k[0][tid], y);
          else             x = fmaf(dt, sh_k[0][tid] - sh_k[1][tid] + sh_k[2][tid], y);
          sh_x[tid] = f2bf(x);
        }
        __syncthreads();
      }

      // ---- L1: h1 = relu(W1 x + b1)  (12 MFMA, 2 acc chains) ----
      {
        f32x4 acc0 = {0.f, 0.f, 0.f, 0.f}, acc1 = {0.f, 0.f, 0.f, 0.f};
        #pragma unroll
        for (int c = 0; c < 12; c += 2) {
          bf16x8 a0 = sh_w1[(w * 12 + c) * 64 + l];
          bf16x8 bb0 = *(const bf16x8*)&sh_x[c * 32 + g * 8];
          acc0 = __builtin_amdgcn_mfma_f32_16x16x32_bf16(a0, bb0, acc0, 0, 0, 0);
          bf16x8 a1 = sh_w1[(w * 12 + c + 1) * 64 + l];
          bf16x8 bb1 = *(const bf16x8*)&sh_x[(c + 1) * 32 + g * 8];
          acc1 = __builtin_amdgcn_mfma_f32_16x16x32_bf16(a1, bb1, acc1, 0, 0, 0);
        }
        f32x4 bv = *(const f32x4*)&sh_b1[16 * w + 4 * g];
        float h0 = fmaxf(acc0[0] + acc1[0] + bv[0], 0.f);
        float h1_ = fmaxf(acc0[1] + acc1[1] + bv[1], 0.f);
        float h2_ = fmaxf(acc0[2] + acc1[2] + bv[2], 0.f);
        float h3 = fmaxf(acc0[3] + acc1[3] + bv[3], 0.f);
        if (r16 == 0) {
          const int base = (16 * w + 4 * g) >> 1;
          sh_h1u[base]     = pk2(h0, h1_);
          sh_h1u[base + 1] = pk2(h2_, h3);
        }
      }
      __syncthreads();

      // ---- L2: h2 = elu(W2 h1 + b2)  (4 MFMA) ----
      {
        f32x4 acc0 = {0.f, 0.f, 0.f, 0.f}, acc1 = {0.f, 0.f, 0.f, 0.f};
        acc0 = __builtin_amdgcn_mfma_f32_16x16x32_bf16(
            w2f[0], *(const bf16x8*)&sh_h1u[0 * 16 + g * 4], acc0, 0, 0, 0);
        acc1 = __builtin_amdgcn_mfma_f32_16x16x32_bf16(
            w2f[1], *(const bf16x8*)&sh_h1u[1 * 16 + g * 4], acc1, 0, 0, 0);
        acc0 = __builtin_amdgcn_mfma_f32_16x16x32_bf16(
            w2f[2], *(const bf16x8*)&sh_h1u[2 * 16 + g * 4], acc0, 0, 0, 0);
        acc1 = __builtin_amdgcn_mfma_f32_16x16x32_bf16(
            w2f[3], *(const bf16x8*)&sh_h1u[3 * 16 + g * 4], acc1, 0, 0, 0);
        f32x4 bv = *(const f32x4*)&sh_b2[16 * w + 4 * g];
        float v0 = acc0[0] + acc1[0] + bv[0]; v0 = v0 > 0.f ? v0 : expm1f(v0);
        float v1 = acc0[1] + acc1[1] + bv[1]; v1 = v1 > 0.f ? v1 : expm1f(v1);
        float v2 = acc0[2] + acc1[2] + bv[2]; v2 = v2 > 0.f ? v2 : expm1f(v2);
        float v3 = acc0[3] + acc1[3] + bv[3]; v3 = v3 > 0.f ? v3 : expm1f(v3);
        if (r16 == 0) {
          const int base = (16 * w + 4 * g) >> 1;
          sh_h2u[base]     = pk2(v0, v1);
          sh_h2u[base + 1] = pk2(v2, v3);
        }
      }
      __syncthreads();

      // ---- L3: k_s = W3 h2 + b3  (12 MFMA, 3 independent row-tiles) ----
      {
        bf16x8 bb[4];
        #pragma unroll
        for (int c = 0; c < 4; ++c)
          bb[c] = *(const bf16x8*)&sh_h2u[c * 16 + g * 4];
        #pragma unroll
        for (int t = 0; t < 3; ++t) {
          f32x4 acc = {0.f, 0.f, 0.f, 0.f};
          #pragma unroll
          for (int c = 0; c < 4; ++c)
            acc = __builtin_amdgcn_mfma_f32_16x16x32_bf16(w3f[t][c], bb[c], acc, 0, 0, 0);
          f32x4 bv = *(const f32x4*)&sh_b3[48 * w + 16 * t + 4 * g];
          if (r16 == 0) {
            f32x4 kv;
            kv[0] = acc[0] + bv[0]; kv[1] = acc[1] + bv[1];
            kv[2] = acc[2] + bv[2]; kv[3] = acc[3] + bv[3];
            *(f32x4*)&sh_k[s][48 * w + 16 * t + 4 * g] = kv;
          }
        }
      }
      __syncthreads();
    } // stages

    // ---- y update + emit coeff for step+1 (also refresh bf16 x for s=0) ----
    if (tid < DD) {
      float y = sh_y[tid];
      y = fmaf(dt * 0.125f,
               sh_k[0][tid] + 3.f * (sh_k[1][tid] + sh_k[2][tid]) + sh_k[3][tid], y);
      sh_y[tid] = y;
      sh_x[tid] = f2bf(y);
      coeffT[(tid % 3) * (KK * NT) + (tid / 3) * NT + (step + 1)] = y;
    }
    __syncthreads();
  }
}

// ---------------- Kernel 2: out[t,m,c,p] = sum_k coeffT[c][k][t]*basis[k,c,p]
__global__ __launch_bounds__(256, 4) void einsum_kernel(
    const float* __restrict__ basis, const float* __restrict__ coeffT,
    float* __restrict__ out)
{
  __shared__ __align__(16) float sh_c[KK * NT];  // [k][t] for this c, 16KB
  const int tid = threadIdx.x;
  const int bid = blockIdx.x;
  const int c = bid >> 8;        // 0..2
  const int ptile = bid & 255;   // 0..255, 256 pixels each

  const float* cT = coeffT + c * (KK * NT);
  #pragma unroll
  for (int q = 0; q < 4; ++q)
    *(float4*)&sh_c[tid * 16 + q * 4] = *(const float4*)&cT[tid * 16 + q * 4];
  __syncthreads();

  const int slot = tid & 31;   // 32 slots x 8 px = 256 px
  const int tg   = tid >> 5;   // 8 groups x 4 t  = 32 t
  const int px0  = ptile * 256 + slot * 8;
  const float* bp = basis + (size_t)c * NPIX + px0;

  float acc[4][8];
  #pragma unroll
  for (int t = 0; t < 4; ++t)
    #pragma unroll
    for (int p = 0; p < 8; ++p) acc[t][p] = 0.f;

  #pragma unroll 4
  for (int k = 0; k < KK; ++k) {
    const float* bk = bp + (size_t)k * (3 * NPIX);
    float4 b0 = *(const float4*)(bk);
    float4 b1v = *(const float4*)(bk + 4);
    float4 cv = *(const float4*)&sh_c[k * NT + tg * 4];
    float cs[4] = {cv.x, cv.y, cv.z, cv.w};
    float bs[8] = {b0.x, b0.y, b0.z, b0.w, b1v.x, b1v.y, b1v.z, b1v.w};
    #pragma unroll
    for (int t = 0; t < 4; ++t)
      #pragma unroll
      for (int p = 0; p < 8; ++p)
        acc[t][p] = fmaf(cs[t], bs[p], acc[t][p]);
  }

  #pragma unroll
  for (int t = 0; t < 4; ++t) {
    const int tt = tg * 4 + t;
    #pragma unroll
    for (int m = 0; m < MBATCH; ++m) {
      float* op = out + (((size_t)(tt * MBATCH + m) * 3 + c) << 16) + px0;
      *(float4*)(op)     = make_float4(acc[t][0], acc[t][1], acc[t][2], acc[t][3]);
      *(float4*)(op + 4) = make_float4(acc[t][4], acc[t][5], acc[t][6], acc[t][7]);
    }
  }
}

extern "C" void kernel_launch(void* const* d_in, const int* in_sizes, int n_in,
                              void* d_out, int out_size, void* d_ws, size_t ws_size,
                              hipStream_t stream) {
  (void)in_sizes; (void)n_in; (void)out_size; (void)ws_size;
  // setup_inputs order: grid0, t, init_coeffs, W1, b1, W2, b2, W3, b3, basis
  const float* tarr  = (const float*)d_in[1];
  const float* ic    = (const float*)d_in[2];
  const float* W1    = (const float*)d_in[3];
  const float* b1    = (const float*)d_in[4];
  const float* W2    = (const float*)d_in[5];
  const float* b2    = (const float*)d_in[6];
  const float* W3    = (const float*)d_in[7];
  const float* b3    = (const float*)d_in[8];
  const float* basis = (const float*)d_in[9];
  float* coeffT = (float*)d_ws;          // 3*128*32 floats = 48 KB
  float* out    = (float*)d_out;

  hipLaunchKernelGGL(ode_kernel, dim3(1), dim3(512), 0, stream,
                     tarr, ic, W1, b1, W2, b2, W3, b3, coeffT);
  hipLaunchKernelGGL(einsum_kernel, dim3(768), dim3(256), 0, stream,
                     basis, coeffT, out);
}